// Round 9
// baseline (201.750 us; speedup 1.0000x reference)
//
#include <hip/hip_runtime.h>

typedef unsigned short u16;
typedef unsigned int u32;
typedef __bf16 bf16x8 __attribute__((ext_vector_type(8)));
typedef float f32x4 __attribute__((ext_vector_type(4)));
typedef float f32x16 __attribute__((ext_vector_type(16)));

#define B_ 16
#define C_ 512
#define N_ 1024
#define NB_ 16384   // B_*N_
#define K_ 512
#define M3_ 1536
#define SCALE_Q 0.18033688011112042f  // 0.125 * log2(e)

// ---- helpers ----
__device__ __forceinline__ u16 f2bf(float f) {
  u32 u = __float_as_uint(f);
  u32 r = (u + 0x7FFFu + ((u >> 16) & 1u)) >> 16;  // RNE
  return (u16)r;
}

__device__ __forceinline__ void gl_lds16(const void* g, void* l) {
  __builtin_amdgcn_global_load_lds(
      (const __attribute__((address_space(1))) u32*)(uintptr_t)g,
      (__attribute__((address_space(3))) u32*)(u32)(uintptr_t)l, 16, 0, 0);
}

__device__ __forceinline__ u32 cvtpk(float lo, float hi) {
  u32 r;
  asm("v_cvt_pk_bf16_f32 %0, %1, %2" : "=v"(r) : "v"(lo), "v"(hi));
  return r;
}

__device__ __forceinline__ float exp2a(float x) {
  float r;
  asm("v_exp_f32 %0, %1" : "=v"(r) : "v"(x));
  return r;
}

// (a,b) -> a' = {a_lo, b_lo}, b' = {a_hi, b_hi}
__device__ __forceinline__ void plswap2(u32& a, u32& b) {
#if __has_builtin(__builtin_amdgcn_permlane32_swap)
  auto r = __builtin_amdgcn_permlane32_swap((int)a, (int)b, false, false);
  a = (u32)r[0];
  b = (u32)r[1];
#else
  asm("v_permlane32_swap_b32 %0, %1" : "+v"(a), "+v"(b));
#endif
}

__device__ __forceinline__ float xhalf_sum(float x) {
  u32 a = __float_as_uint(x), b = a;
  plswap2(a, b);
  return __uint_as_float(a) + __uint_as_float(b);
}

// ---- kernel 1: fp32 -> bf16 cast for weights ----
__global__ __launch_bounds__(256) void cast_bf16_kernel(const float* __restrict__ src,
                                                        u16* __restrict__ dst, int n) {
  int i = blockIdx.x * 256 + threadIdx.x;
  if (i < n) dst[i] = f2bf(src[i]);
}

// ---- kernel 2: GroupNorm, writes h^T as (B*N, C) bf16 ----
__global__ __launch_bounds__(256) void gnorm_kernel(const float* __restrict__ x,
                                                    const float* __restrict__ gamma,
                                                    const float* __restrict__ beta,
                                                    u16* __restrict__ ht) {
  int blk = blockIdx.x;
  int b = blk >> 5, g = blk & 31;
  int t = threadIdx.x;
  const float* xb = x + ((size_t)(b * C_ + g * 16) << 10);
  float v[16][4];
  float s = 0.f, sq = 0.f;
#pragma unroll
  for (int cc = 0; cc < 16; ++cc) {
#pragma unroll
    for (int r = 0; r < 4; ++r) {
      float f = xb[cc * 1024 + r * 256 + t];
      v[cc][r] = f; s += f; sq += f * f;
    }
  }
#pragma unroll
  for (int m = 32; m >= 1; m >>= 1) { s += __shfl_xor(s, m, 64); sq += __shfl_xor(sq, m, 64); }
  __shared__ float red[8];
  int w = t >> 6;
  if ((t & 63) == 0) { red[w * 2] = s; red[w * 2 + 1] = sq; }
  __syncthreads();
  s = red[0] + red[2] + red[4] + red[6];
  sq = red[1] + red[3] + red[5] + red[7];
  float mean = s * (1.f / 16384.f);
  float var = sq * (1.f / 16384.f) - mean * mean;
  float rstd = rsqrtf(var + 1e-5f);
  float gm[16], bt[16];
#pragma unroll
  for (int cc = 0; cc < 16; ++cc) {
    gm[cc] = gamma[g * 16 + cc] * rstd;
    bt[cc] = beta[g * 16 + cc];
  }
  u16* hb = ht + ((size_t)(b << 10)) * C_ + g * 16;
#pragma unroll
  for (int r = 0; r < 4; ++r) {
    u32 pk[8];
#pragma unroll
    for (int q = 0; q < 8; ++q) {
      float f0 = (v[2 * q][r] - mean) * gm[2 * q] + bt[2 * q];
      float f1 = (v[2 * q + 1][r] - mean) * gm[2 * q + 1] + bt[2 * q + 1];
      pk[q] = (u32)f2bf(f0) | ((u32)f2bf(f1) << 16);
    }
    u16* dp = hb + (size_t)(r * 256 + t) * C_;
    uint4 a = {pk[0], pk[1], pk[2], pk[3]};
    uint4 b4 = {pk[4], pk[5], pk[6], pk[7]};
    *(uint4*)dp = a;
    *(uint4*)(dp + 8) = b4;
  }
}

// ---- GEMM (r6 version): C[MxNB] = A[MxK] * BT[NBxK]^T ; 128x128 tile, BK=64 ----
// EPI 0: qkv GEMM. q,k bands (rows<1024) stored TRANSPOSED per-(b,h) as (n,d)
//        bf16 into qTo/kTo (q pre-scaled); v band stored (o, bn) in Co.
// EPI 1: out = x + val + bias -> fp32 (b,c,n)
template <int EPI>
__global__ __launch_bounds__(256) void gemm_kernel(const u16* __restrict__ A,
                                                   const u16* __restrict__ BT,
                                                   const float* __restrict__ bias,
                                                   u16* __restrict__ Co,
                                                   u16* __restrict__ qTo,
                                                   u16* __restrict__ kTo,
                                                   const float* __restrict__ xres,
                                                   float* __restrict__ Fo) {
  __shared__ u16 ldsA[128 * 64];
  __shared__ u16 ldsB[128 * 64];
  int t = threadIdx.x;
  int l = t & 63, w = t >> 6;
  int wr = w >> 1, wc = w & 1;
  int ro0 = blockIdx.y * 128, co0 = blockIdx.x * 128;
  f32x4 acc[4][4];
#pragma unroll
  for (int m = 0; m < 4; ++m)
#pragma unroll
    for (int n = 0; n < 4; ++n) acc[m][n] = {0.f, 0.f, 0.f, 0.f};
  int srow = t >> 3, sg = t & 7;
  for (int kt = 0; kt < 8; ++kt) {
    int k0 = kt * 64;
#pragma unroll
    for (int i = 0; i < 4; ++i) {
      int row = i * 32 + srow;
      int gl = sg ^ (row & 7);
      gl_lds16(A + (size_t)(ro0 + row) * K_ + k0 + gl * 8, ldsA + (i * 32 + w * 8) * 64);
      gl_lds16(BT + (size_t)(co0 + row) * K_ + k0 + gl * 8, ldsB + (i * 32 + w * 8) * 64);
    }
    __syncthreads();
#pragma unroll
    for (int ks = 0; ks < 2; ++ks) {
      bf16x8 af[4], bfr[4];
#pragma unroll
      for (int m = 0; m < 4; ++m) {
        int row = wr * 64 + m * 16 + (l & 15);
        int ph = (ks * 4 + (l >> 4)) ^ (row & 7);
        af[m] = *(const bf16x8*)&ldsA[row * 64 + ph * 8];
      }
#pragma unroll
      for (int n = 0; n < 4; ++n) {
        int row = wc * 64 + n * 16 + (l & 15);
        int ph = (ks * 4 + (l >> 4)) ^ (row & 7);
        bfr[n] = *(const bf16x8*)&ldsB[row * 64 + ph * 8];
      }
#pragma unroll
      for (int m = 0; m < 4; ++m)
#pragma unroll
        for (int n = 0; n < 4; ++n)
          acc[m][n] = __builtin_amdgcn_mfma_f32_16x16x32_bf16(af[m], bfr[n], acc[m][n], 0, 0, 0);
    }
    __syncthreads();
  }
  if (EPI == 0 && ro0 < 1024) {
    // q/k band: transposed store into (b,h)(n,d) layout
    int sel = ro0 >> 9;
    u16* dstb = sel ? kTo : qTo;
    float scl = sel ? 1.f : SCALE_Q;
#pragma unroll
    for (int m = 0; m < 4; ++m) {
      int row0 = ro0 + wr * 64 + m * 16 + (l >> 4) * 4;
      int o = row0 & 511;
      int h = o >> 6, d0 = o & 63;
      float bv0 = bias[row0], bv1 = bias[row0 + 1];
      float bv2 = bias[row0 + 2], bv3 = bias[row0 + 3];
#pragma unroll
      for (int n = 0; n < 4; ++n) {
        int col = co0 + wc * 64 + n * 16 + (l & 15);
        int bb = col >> 10, nn = col & 1023;
        float v0 = (acc[m][n][0] + bv0) * scl;
        float v1 = (acc[m][n][1] + bv1) * scl;
        float v2 = (acc[m][n][2] + bv2) * scl;
        float v3 = (acc[m][n][3] + bv3) * scl;
        uint2 ov = {cvtpk(v0, v1), cvtpk(v2, v3)};
        *(uint2*)(dstb + ((size_t)((bb * 8 + h) << 10) + nn) * 64 + d0) = ov;
      }
    }
  } else {
#pragma unroll
    for (int m = 0; m < 4; ++m) {
#pragma unroll
      for (int j = 0; j < 4; ++j) {
        int row = ro0 + wr * 64 + m * 16 + (l >> 4) * 4 + j;
        float bv = bias[row];
#pragma unroll
        for (int n = 0; n < 4; ++n) {
          int col = co0 + wc * 64 + n * 16 + (l & 15);
          float val = acc[m][n][j] + bv;
          if (EPI == 0) {
            Co[(size_t)row * NB_ + col] = f2bf(val);
          } else {
            int bb = col >> 10, nn = col & 1023;
            size_t oi = (((size_t)(bb * C_ + row)) << 10) + nn;
            Fo[oi] = xres[oi] + val;
          }
        }
      }
    }
  }
}

// ---- kernel 4: flash attention, NO LDS: K/V read direct from L2 ----
// K+V per head = 256KB (L2-resident; 8 q-tile blocks of the same head share an
// XCD via the swizzle). Fragments are the same per-lane 16B chunks the LDS path
// delivered, so all MFMA math is unchanged. Waves fully independent: no
// barriers, no staging, no bank conflicts. Register double-buffer (named sets,
// no runtime indexing) prefetches tile s+1 ~1.5 steps ahead; compiler-managed
// waitcnt covers the ~200cyc L2 latency.
__global__ __launch_bounds__(256) void attn_kernel(const u16* __restrict__ qT,
                                                   const u16* __restrict__ kT,
                                                   const u16* __restrict__ qkv,
                                                   u16* __restrict__ aoT) {
  int bid = blockIdx.x;
  int wid = (bid & 7) * 128 + (bid >> 3);  // XCD swizzle: 8 blocks of a head on one XCD
  int qt2 = wid & 7, h = (wid >> 3) & 7, b = wid >> 6;
  int bh = b * 8 + h;
  int t = threadIdx.x, l = t & 63, w = t >> 6;
  int lq = l & 31, hi = l >> 5;
  int q0 = qt2 * 128 + w * 32;

  // Q fragments (scale pre-folded in qkv GEMM epilogue)
  const u16* qbase = qT + ((size_t)(bh << 10) + q0 + lq) * 64 + hi * 8;
  bf16x8 qf[4];
#pragma unroll
  for (int kc = 0; kc < 4; ++kc) qf[kc] = *(const bf16x8*)(qbase + kc * 16);

  f32x16 accO[2];
#pragma unroll
  for (int dt = 0; dt < 2; ++dt)
#pragma unroll
    for (int r = 0; r < 16; ++r) accO[dt][r] = 0.f;
  float lsum = 0.f;

  // fragment source bases
  // K: lane reads K[kv = mt*32+lq][d = kc*16 + hi*8 .. +8]
  const u16* kfb = kT + ((size_t)(bh << 10) + lq) * 64 + hi * 8;
  // V: lane reads V^T[d = dt*32+lq][kv = mt*32 + kcc*16 + hi*8 .. +8]
  const u16* vfb = qkv + (size_t)(2 * C_ + h * 64 + lq) * NB_ + (b << 10) + hi * 8;

  auto loadK = [&](bf16x8* dst, int mt) {
    const u16* p = kfb + (size_t)(mt * 32) * 64;
#pragma unroll
    for (int kc = 0; kc < 4; ++kc) dst[kc] = *(const bf16x8*)(p + kc * 16);
  };
  auto loadV = [&](bf16x8* dst, int mt) {
    const u16* p = vfb + mt * 32;
#pragma unroll
    for (int dt = 0; dt < 2; ++dt)
#pragma unroll
      for (int kcc = 0; kcc < 2; ++kcc)
        dst[dt * 2 + kcc] = *(const bf16x8*)(p + (size_t)(dt * 32) * NB_ + kcc * 16);
  };

  auto step = [&](const bf16x8* kf, const bf16x8* vf) {
    f32x16 sc;
#pragma unroll
    for (int r = 0; r < 16; ++r) sc[r] = 0.f;
    __builtin_amdgcn_s_setprio(1);
#pragma unroll
    for (int kc = 0; kc < 4; ++kc)
      sc = __builtin_amdgcn_mfma_f32_32x32x16_bf16(kf[kc], qf[kc], sc, 0, 0, 0);
    __builtin_amdgcn_s_setprio(0);
    // P = exp2(S); log2-domain scores, constant shift cancels in O = PV / sum P
    float p0 = 0.f, p1 = 0.f, p2 = 0.f, p3 = 0.f;
#pragma unroll
    for (int r = 0; r < 4; ++r) {
      float e0 = exp2a(sc[4 * r + 0]);
      float e1 = exp2a(sc[4 * r + 1]);
      float e2 = exp2a(sc[4 * r + 2]);
      float e3 = exp2a(sc[4 * r + 3]);
      sc[4 * r + 0] = e0; sc[4 * r + 1] = e1;
      sc[4 * r + 2] = e2; sc[4 * r + 3] = e3;
      p0 += e0; p1 += e1; p2 += e2; p3 += e3;
    }
    lsum += (p0 + p1) + (p2 + p3);
    u32 pk[8];
#pragma unroll
    for (int p = 0; p < 8; ++p) pk[p] = cvtpk(sc[2 * p], sc[2 * p + 1]);
    u32 pfu[2][4];
#pragma unroll
    for (int cc = 0; cc < 2; ++cc) {
      u32 w0 = pk[cc * 4 + 0], w2 = pk[cc * 4 + 2];
      u32 w1 = pk[cc * 4 + 1], w3 = pk[cc * 4 + 3];
      plswap2(w0, w2);
      plswap2(w1, w3);
      pfu[cc][0] = w0; pfu[cc][1] = w1; pfu[cc][2] = w2; pfu[cc][3] = w3;
    }
    __builtin_amdgcn_s_setprio(1);
#pragma unroll
    for (int kcc = 0; kcc < 2; ++kcc)
#pragma unroll
      for (int dt = 0; dt < 2; ++dt) {
        union { u32 u[4]; bf16x8 v; } pf;
        pf.u[0] = pfu[kcc][0]; pf.u[1] = pfu[kcc][1];
        pf.u[2] = pfu[kcc][2]; pf.u[3] = pfu[kcc][3];
        accO[dt] = __builtin_amdgcn_mfma_f32_32x32x16_bf16(vf[dt * 2 + kcc], pf.v, accO[dt], 0, 0, 0);
      }
    __builtin_amdgcn_s_setprio(0);
  };

  // register double-buffer, named sets (no runtime indexing -> no scratch)
  bf16x8 ka[4], va[4], kb[4], vb[4];
  loadK(ka, 0); loadV(va, 0);
  loadK(kb, 1); loadV(vb, 1);
#pragma unroll 1
  for (int s = 0; s < 15; ++s) {
    step(ka, va);
    loadK(ka, 2 * s + 2); loadV(va, 2 * s + 2);
    step(kb, vb);
    loadK(kb, 2 * s + 3); loadV(vb, 2 * s + 3);
  }
  step(ka, va);  // tile 30
  step(kb, vb);  // tile 31

  float inv = 1.0f / xhalf_sum(lsum);
  u16* ob = aoT + ((size_t)((b << 10) + q0 + lq)) * C_ + h * 64;
#pragma unroll
  for (int dt = 0; dt < 2; ++dt)
#pragma unroll
    for (int rg = 0; rg < 4; ++rg) {
      int d0 = dt * 32 + rg * 8 + hi * 4;
      u32 w0 = cvtpk(accO[dt][rg * 4 + 0] * inv, accO[dt][rg * 4 + 1] * inv);
      u32 w1 = cvtpk(accO[dt][rg * 4 + 2] * inv, accO[dt][rg * 4 + 3] * inv);
      uint2 o = {w0, w1};
      *(uint2*)(ob + d0) = o;
    }
}

// ---- launcher ----
extern "C" void kernel_launch(void* const* d_in, const int* in_sizes, int n_in,
                              void* d_out, int out_size, void* d_ws, size_t ws_size,
                              hipStream_t stream) {
  const float* x = (const float*)d_in[0];
  const float* gamma = (const float*)d_in[1];
  const float* beta = (const float*)d_in[2];
  const float* qkv_w = (const float*)d_in[3];
  const float* qkv_b = (const float*)d_in[4];
  const float* proj_w = (const float*)d_in[5];
  const float* proj_b = (const float*)d_in[6];
  float* out = (float*)d_out;
  char* ws = (char*)d_ws;
  u16* wq = (u16*)(ws);                      // 1,572,864
  u16* wp = (u16*)(ws + 1572864);            //   524,288
  u16* ht = (u16*)(ws + 2097152);            // 16,777,216 (reused as aoT)
  u16* qkvo = (u16*)(ws + 18874368);         // 50,331,648 (only v band used)
  u16* qT = (u16*)(ws + 69206016);           // 16,777,216
  u16* kT = (u16*)(ws + 85983232);           // 16,777,216
  u16* aoT = ht;

  cast_bf16_kernel<<<3072, 256, 0, stream>>>(qkv_w, wq, M3_ * K_);
  cast_bf16_kernel<<<1024, 256, 0, stream>>>(proj_w, wp, C_ * K_);
  gnorm_kernel<<<512, 256, 0, stream>>>(x, gamma, beta, ht);
  gemm_kernel<0><<<dim3(128, 12), 256, 0, stream>>>(wq, ht, qkv_b, qkvo, qT, kT, nullptr, nullptr);
  attn_kernel<<<1024, 256, 0, stream>>>(qT, kT, qkvo, aoT);
  gemm_kernel<1><<<dim3(128, 4), 256, 0, stream>>>(wp, aoT, proj_b, nullptr, nullptr, nullptr, x, out);
}

// Round 10
// 130.411 us; speedup vs baseline: 1.5470x; 1.5470x over previous
//
#include <hip/hip_runtime.h>

typedef unsigned short u16;
typedef unsigned int u32;
typedef __bf16 bf16x8 __attribute__((ext_vector_type(8)));
typedef float f32x4 __attribute__((ext_vector_type(4)));
typedef float f32x16 __attribute__((ext_vector_type(16)));

#define B_ 16
#define C_ 512
#define N_ 1024
#define NB_ 16384   // B_*N_
#define K_ 512
#define M3_ 1536
#define SCALE_Q 0.18033688011112042f  // 0.125 * log2(e)

// ---- helpers ----
__device__ __forceinline__ u16 f2bf(float f) {
  u32 u = __float_as_uint(f);
  u32 r = (u + 0x7FFFu + ((u >> 16) & 1u)) >> 16;  // RNE
  return (u16)r;
}

__device__ __forceinline__ void gl_lds16(const void* g, void* l) {
  __builtin_amdgcn_global_load_lds(
      (const __attribute__((address_space(1))) u32*)(uintptr_t)g,
      (__attribute__((address_space(3))) u32*)(u32)(uintptr_t)l, 16, 0, 0);
}

__device__ __forceinline__ u32 cvtpk(float lo, float hi) {
  u32 r;
  asm("v_cvt_pk_bf16_f32 %0, %1, %2" : "=v"(r) : "v"(lo), "v"(hi));
  return r;
}

__device__ __forceinline__ float exp2a(float x) {
  float r;
  asm("v_exp_f32 %0, %1" : "=v"(r) : "v"(x));
  return r;
}

// (a,b) -> a' = {a_lo, b_lo}, b' = {a_hi, b_hi}
__device__ __forceinline__ void plswap2(u32& a, u32& b) {
#if __has_builtin(__builtin_amdgcn_permlane32_swap)
  auto r = __builtin_amdgcn_permlane32_swap((int)a, (int)b, false, false);
  a = (u32)r[0];
  b = (u32)r[1];
#else
  asm("v_permlane32_swap_b32 %0, %1" : "+v"(a), "+v"(b));
#endif
}

__device__ __forceinline__ float xhalf_sum(float x) {
  u32 a = __float_as_uint(x), b = a;
  plswap2(a, b);
  return __uint_as_float(a) + __uint_as_float(b);
}

// ---- kernel 1: fp32 -> bf16 cast for both weight matrices (one launch) ----
__global__ __launch_bounds__(256) void cast2_kernel(const float* __restrict__ a,
                                                    const float* __restrict__ b,
                                                    u16* __restrict__ da,
                                                    u16* __restrict__ db,
                                                    int na, int nb) {
  int i = blockIdx.x * 256 + threadIdx.x;
  if (i < na) {
    da[i] = f2bf(a[i]);
  } else {
    int j = i - na;
    if (j < nb) db[j] = f2bf(b[j]);
  }
}

// ---- kernel 2: GroupNorm, writes h^T as (B*N, C) bf16 ----
__global__ __launch_bounds__(256) void gnorm_kernel(const float* __restrict__ x,
                                                    const float* __restrict__ gamma,
                                                    const float* __restrict__ beta,
                                                    u16* __restrict__ ht) {
  int blk = blockIdx.x;
  int b = blk >> 5, g = blk & 31;
  int t = threadIdx.x;
  const float* xb = x + ((size_t)(b * C_ + g * 16) << 10);
  float v[16][4];
  float s = 0.f, sq = 0.f;
#pragma unroll
  for (int cc = 0; cc < 16; ++cc) {
#pragma unroll
    for (int r = 0; r < 4; ++r) {
      float f = xb[cc * 1024 + r * 256 + t];
      v[cc][r] = f; s += f; sq += f * f;
    }
  }
#pragma unroll
  for (int m = 32; m >= 1; m >>= 1) { s += __shfl_xor(s, m, 64); sq += __shfl_xor(sq, m, 64); }
  __shared__ float red[8];
  int w = t >> 6;
  if ((t & 63) == 0) { red[w * 2] = s; red[w * 2 + 1] = sq; }
  __syncthreads();
  s = red[0] + red[2] + red[4] + red[6];
  sq = red[1] + red[3] + red[5] + red[7];
  float mean = s * (1.f / 16384.f);
  float var = sq * (1.f / 16384.f) - mean * mean;
  float rstd = rsqrtf(var + 1e-5f);
  float gm[16], bt[16];
#pragma unroll
  for (int cc = 0; cc < 16; ++cc) {
    gm[cc] = gamma[g * 16 + cc] * rstd;
    bt[cc] = beta[g * 16 + cc];
  }
  u16* hb = ht + ((size_t)(b << 10)) * C_ + g * 16;
#pragma unroll
  for (int r = 0; r < 4; ++r) {
    u32 pk[8];
#pragma unroll
    for (int q = 0; q < 8; ++q) {
      float f0 = (v[2 * q][r] - mean) * gm[2 * q] + bt[2 * q];
      float f1 = (v[2 * q + 1][r] - mean) * gm[2 * q + 1] + bt[2 * q + 1];
      pk[q] = (u32)f2bf(f0) | ((u32)f2bf(f1) << 16);
    }
    u16* dp = hb + (size_t)(r * 256 + t) * C_;
    uint4 a = {pk[0], pk[1], pk[2], pk[3]};
    uint4 b4 = {pk[4], pk[5], pk[6], pk[7]};
    *(uint4*)dp = a;
    *(uint4*)(dp + 8) = b4;
  }
}

// ---- GEMM (r6 body + XCD swizzle): C[MxNB] = A[MxK]*BT[NBxK]^T; 128x128, BK=64 ----
// XCD swizzle: linear block id % 8 = XCD; give each XCD 16 column-panels x all
// row-blocks so B-panels are L2-private (T1). Requires gridDim.x == 128.
// EPI 0: qkv GEMM. q,k bands (rows<1024) stored TRANSPOSED per-(b,h) as (n,d)
//        bf16 into qTo/kTo (q pre-scaled); v band stored (o, bn) in Co.
// EPI 1: out = x + val + bias -> fp32 (b,c,n)
template <int EPI>
__global__ __launch_bounds__(256) void gemm_kernel(const u16* __restrict__ A,
                                                   const u16* __restrict__ BT,
                                                   const float* __restrict__ bias,
                                                   u16* __restrict__ Co,
                                                   u16* __restrict__ qTo,
                                                   u16* __restrict__ kTo,
                                                   const float* __restrict__ xres,
                                                   float* __restrict__ Fo) {
  __shared__ u16 ldsA[128 * 64];
  __shared__ u16 ldsB[128 * 64];
  int t = threadIdx.x;
  int l = t & 63, w = t >> 6;
  int wr = w >> 1, wc = w & 1;
  int lid = blockIdx.y * 128 + blockIdx.x;
  int xcd = lid & 7, j2 = lid >> 3;
  int bx = xcd * 16 + (j2 & 15);
  int by = j2 >> 4;
  int ro0 = by * 128, co0 = bx * 128;
  f32x4 acc[4][4];
#pragma unroll
  for (int m = 0; m < 4; ++m)
#pragma unroll
    for (int n = 0; n < 4; ++n) acc[m][n] = {0.f, 0.f, 0.f, 0.f};
  int srow = t >> 3, sg = t & 7;
  for (int kt = 0; kt < 8; ++kt) {
    int k0 = kt * 64;
#pragma unroll
    for (int i = 0; i < 4; ++i) {
      int row = i * 32 + srow;
      int gl = sg ^ (row & 7);
      gl_lds16(A + (size_t)(ro0 + row) * K_ + k0 + gl * 8, ldsA + (i * 32 + w * 8) * 64);
      gl_lds16(BT + (size_t)(co0 + row) * K_ + k0 + gl * 8, ldsB + (i * 32 + w * 8) * 64);
    }
    __syncthreads();
#pragma unroll
    for (int ks = 0; ks < 2; ++ks) {
      bf16x8 af[4], bfr[4];
#pragma unroll
      for (int m = 0; m < 4; ++m) {
        int row = wr * 64 + m * 16 + (l & 15);
        int ph = (ks * 4 + (l >> 4)) ^ (row & 7);
        af[m] = *(const bf16x8*)&ldsA[row * 64 + ph * 8];
      }
#pragma unroll
      for (int n = 0; n < 4; ++n) {
        int row = wc * 64 + n * 16 + (l & 15);
        int ph = (ks * 4 + (l >> 4)) ^ (row & 7);
        bfr[n] = *(const bf16x8*)&ldsB[row * 64 + ph * 8];
      }
#pragma unroll
      for (int m = 0; m < 4; ++m)
#pragma unroll
        for (int n = 0; n < 4; ++n)
          acc[m][n] = __builtin_amdgcn_mfma_f32_16x16x32_bf16(af[m], bfr[n], acc[m][n], 0, 0, 0);
    }
    __syncthreads();
  }
  if (EPI == 0 && ro0 < 1024) {
    // q/k band: transposed store into (b,h)(n,d) layout
    int sel = ro0 >> 9;
    u16* dstb = sel ? kTo : qTo;
    float scl = sel ? 1.f : SCALE_Q;
#pragma unroll
    for (int m = 0; m < 4; ++m) {
      int row0 = ro0 + wr * 64 + m * 16 + (l >> 4) * 4;
      int o = row0 & 511;
      int h = o >> 6, d0 = o & 63;
      float bv0 = bias[row0], bv1 = bias[row0 + 1];
      float bv2 = bias[row0 + 2], bv3 = bias[row0 + 3];
#pragma unroll
      for (int n = 0; n < 4; ++n) {
        int col = co0 + wc * 64 + n * 16 + (l & 15);
        int bb = col >> 10, nn = col & 1023;
        float v0 = (acc[m][n][0] + bv0) * scl;
        float v1 = (acc[m][n][1] + bv1) * scl;
        float v2 = (acc[m][n][2] + bv2) * scl;
        float v3 = (acc[m][n][3] + bv3) * scl;
        uint2 ov = {cvtpk(v0, v1), cvtpk(v2, v3)};
        *(uint2*)(dstb + ((size_t)((bb * 8 + h) << 10) + nn) * 64 + d0) = ov;
      }
    }
  } else {
#pragma unroll
    for (int m = 0; m < 4; ++m) {
#pragma unroll
      for (int j = 0; j < 4; ++j) {
        int row = ro0 + wr * 64 + m * 16 + (l >> 4) * 4 + j;
        float bv = bias[row];
#pragma unroll
        for (int n = 0; n < 4; ++n) {
          int col = co0 + wc * 64 + n * 16 + (l & 15);
          float val = acc[m][n][j] + bv;
          if (EPI == 0) {
            Co[(size_t)row * NB_ + col] = f2bf(val);
          } else {
            int bb = col >> 10, nn = col & 1023;
            size_t oi = (((size_t)(bb * C_ + row)) << 10) + nn;
            Fo[oi] = xres[oi] + val;
          }
        }
      }
    }
  }
}

// ---- kernel 4: flash attention, 4 waves x 32 q-rows, KVBLK=64 ----
// r6 staging discipline (vmcnt(0) own loads -> s_barrier -> stage(buf^1) ->
// compute), r2's verified two-chunk S + pack math. 16 steps (vs 32): halves
// barrier/vmcnt sync overhead, same total LDS/MFMA/VALU work.
__global__ __launch_bounds__(256) void attn_kernel(const u16* __restrict__ qT,
                                                   const u16* __restrict__ kT,
                                                   const u16* __restrict__ qkv,
                                                   u16* __restrict__ aoT) {
  __shared__ u16 KV[2][8192];  // [buf][0..4095 = K(64kv x 64d) | 4096..8191 = V(64d x 64kv)]
  int bid = blockIdx.x;
  int wid = (bid & 7) * 128 + (bid >> 3);  // XCD swizzle: 8 blocks of a head on one XCD
  int qt2 = wid & 7, h = (wid >> 3) & 7, b = wid >> 6;
  int bh = b * 8 + h;
  int t = threadIdx.x, l = t & 63, w = t >> 6;
  int lq = l & 31, hi = l >> 5;
  int q0 = qt2 * 128 + w * 32;

  // Q fragments (scale pre-folded in qkv GEMM epilogue)
  const u16* qbase = qT + ((size_t)(bh << 10) + q0 + lq) * 64 + hi * 8;
  bf16x8 qf[4];
#pragma unroll
  for (int kc = 0; kc < 4; ++kc) qf[kc] = *(const bf16x8*)(qbase + kc * 16);

  f32x16 accO[2];
#pragma unroll
  for (int dt = 0; dt < 2; ++dt)
#pragma unroll
    for (int r = 0; r < 16; ++r) accO[dt][r] = 0.f;
  float lsum = 0.f;

  // staging: 16 gl_lds16 per tile, wave w issues 4.
  // waves 0,1 -> K rows 32w + i*8 + (l>>3); waves 2,3 -> V d-rows 32(w-2) + i*8 + (l>>3).
  // Both use granule key (l&7)^((l>>3)&7) == (l&7)^(row&7); LDS[64*row + 8*slot]
  // holds granule slot^(row&7)  (linear dest <-> pre-swizzled source).
  const u16* src;
  u32 ldso;
  size_t gstep;
  int adv;
  if (w < 2) {
    src = kT + ((size_t)(bh << 10) + 32 * w + (l >> 3)) * 64 + (((l & 7) ^ ((l >> 3) & 7)) * 8);
    ldso = 2048u * w;
    gstep = 512;           // +8 rows
    adv = 4096;            // +64 kv-rows per tile
  } else {
    src = qkv + (size_t)(2 * C_ + h * 64 + 32 * (w - 2) + (l >> 3)) * NB_ + (b << 10) +
          (((l & 7) ^ ((l >> 3) & 7)) * 8);
    ldso = 4096 + 2048u * (w - 2);
    gstep = (size_t)8 * NB_;  // +8 d-rows
    adv = 64;              // +64 kv-cols per tile
  }

  // LDS read offsets (buf 0; buf 1 = +8192 elems)
  const u16* kfp[8];  // [c*4+kc]: K[kk=c*32+lq][granule 2kc+hi], slot = phase^(lq&7)
#pragma unroll
  for (int c = 0; c < 2; ++c)
#pragma unroll
    for (int kc = 0; kc < 4; ++kc)
      kfp[c * 4 + kc] = &KV[0][0] + (c * 32 + lq) * 64 + (((2 * kc + hi) ^ (lq & 7)) * 8);
  const u16* vfp[8];  // [dt*4+kcc]: V^T[d=dt*32+lq][granule 2kcc+hi]
#pragma unroll
  for (int dt = 0; dt < 2; ++dt)
#pragma unroll
    for (int kcc = 0; kcc < 4; ++kcc)
      vfp[dt * 4 + kcc] = &KV[0][0] + 4096 + (dt * 32 + lq) * 64 +
                          (((2 * kcc + hi) ^ (lq & 7)) * 8);

  auto stage = [&](int buf) {
#pragma unroll
    for (int i = 0; i < 4; ++i) gl_lds16(src + i * gstep, &KV[buf][0] + ldso + i * 512);
    src += adv;
  };

  auto step = [&](int buf, bool dostage) {
    asm volatile("s_waitcnt vmcnt(0)" ::: "memory");  // own 4 loads of tile s landed
    __builtin_amdgcn_sched_barrier(0);
    __builtin_amdgcn_s_barrier();                     // all 16 staging writes landed
    __builtin_amdgcn_sched_barrier(0);
    if (dostage) stage(buf ^ 1);                      // prefetch tile s+1 into other buf
    bf16x8 kf0[4], kf1[4];
#pragma unroll
    for (int kc = 0; kc < 4; ++kc) {
      kf0[kc] = *(const bf16x8*)(kfp[kc] + buf * 8192);
      kf1[kc] = *(const bf16x8*)(kfp[4 + kc] + buf * 8192);
    }
    f32x16 sc0, sc1;
#pragma unroll
    for (int r = 0; r < 16; ++r) { sc0[r] = 0.f; sc1[r] = 0.f; }
    __builtin_amdgcn_s_setprio(1);
#pragma unroll
    for (int kc = 0; kc < 4; ++kc) {
      sc0 = __builtin_amdgcn_mfma_f32_32x32x16_bf16(kf0[kc], qf[kc], sc0, 0, 0, 0);
      sc1 = __builtin_amdgcn_mfma_f32_32x32x16_bf16(kf1[kc], qf[kc], sc1, 0, 0, 0);
    }
    __builtin_amdgcn_s_setprio(0);
    bf16x8 vf[8];
#pragma unroll
    for (int i = 0; i < 8; ++i) vf[i] = *(const bf16x8*)(vfp[i] + buf * 8192);
    // P = exp2(S); log2-domain scores, constant shift cancels in O = PV / sum P
    float p0 = 0.f, p1 = 0.f, p2 = 0.f, p3 = 0.f;
#pragma unroll
    for (int r = 0; r < 4; ++r) {
      float e0 = exp2a(sc0[4 * r + 0]);
      float e1 = exp2a(sc0[4 * r + 1]);
      float e2 = exp2a(sc0[4 * r + 2]);
      float e3 = exp2a(sc0[4 * r + 3]);
      sc0[4 * r + 0] = e0; sc0[4 * r + 1] = e1;
      sc0[4 * r + 2] = e2; sc0[4 * r + 3] = e3;
      p0 += e0; p1 += e1; p2 += e2; p3 += e3;
    }
#pragma unroll
    for (int r = 0; r < 4; ++r) {
      float e0 = exp2a(sc1[4 * r + 0]);
      float e1 = exp2a(sc1[4 * r + 1]);
      float e2 = exp2a(sc1[4 * r + 2]);
      float e3 = exp2a(sc1[4 * r + 3]);
      sc1[4 * r + 0] = e0; sc1[4 * r + 1] = e1;
      sc1[4 * r + 2] = e2; sc1[4 * r + 3] = e3;
      p0 += e0; p1 += e1; p2 += e2; p3 += e3;
    }
    lsum += (p0 + p1) + (p2 + p3);
    // pack chunk c -> P fragments for kv-slots kcc = c*2+cc, then PV (r2-verified)
#pragma unroll
    for (int c = 0; c < 2; ++c) {
      const f32x16& scc = c ? sc1 : sc0;
      u32 pk[8];
#pragma unroll
      for (int p = 0; p < 8; ++p) pk[p] = cvtpk(scc[2 * p], scc[2 * p + 1]);
      u32 pfu[2][4];
#pragma unroll
      for (int cc = 0; cc < 2; ++cc) {
        u32 w0 = pk[cc * 4 + 0], w2 = pk[cc * 4 + 2];
        u32 w1 = pk[cc * 4 + 1], w3 = pk[cc * 4 + 3];
        plswap2(w0, w2);
        plswap2(w1, w3);
        pfu[cc][0] = w0; pfu[cc][1] = w1; pfu[cc][2] = w2; pfu[cc][3] = w3;
      }
      __builtin_amdgcn_s_setprio(1);
#pragma unroll
      for (int cc = 0; cc < 2; ++cc) {
        int kcc = c * 2 + cc;
        union { u32 u[4]; bf16x8 v; } pf;
        pf.u[0] = pfu[cc][0]; pf.u[1] = pfu[cc][1];
        pf.u[2] = pfu[cc][2]; pf.u[3] = pfu[cc][3];
        accO[0] = __builtin_amdgcn_mfma_f32_32x32x16_bf16(vf[kcc], pf.v, accO[0], 0, 0, 0);
        accO[1] = __builtin_amdgcn_mfma_f32_32x32x16_bf16(vf[4 + kcc], pf.v, accO[1], 0, 0, 0);
      }
      __builtin_amdgcn_s_setprio(0);
    }
  };

  stage(0);  // prefetch tile 0 into buf 0
#pragma unroll 1
  for (int s = 0; s < 7; ++s) {
    step(0, true);
    step(1, true);
  }
  step(0, true);   // tile 14, prefetch 15
  step(1, false);  // tile 15

  float inv = 1.0f / xhalf_sum(lsum);
  u16* ob = aoT + ((size_t)((b << 10) + q0 + lq)) * C_ + h * 64;
#pragma unroll
  for (int dt = 0; dt < 2; ++dt)
#pragma unroll
    for (int rg = 0; rg < 4; ++rg) {
      int d0 = dt * 32 + rg * 8 + hi * 4;
      u32 w0 = cvtpk(accO[dt][rg * 4 + 0] * inv, accO[dt][rg * 4 + 1] * inv);
      u32 w1 = cvtpk(accO[dt][rg * 4 + 2] * inv, accO[dt][rg * 4 + 3] * inv);
      uint2 o = {w0, w1};
      *(uint2*)(ob + d0) = o;
    }
}

// ---- launcher ----
extern "C" void kernel_launch(void* const* d_in, const int* in_sizes, int n_in,
                              void* d_out, int out_size, void* d_ws, size_t ws_size,
                              hipStream_t stream) {
  const float* x = (const float*)d_in[0];
  const float* gamma = (const float*)d_in[1];
  const float* beta = (const float*)d_in[2];
  const float* qkv_w = (const float*)d_in[3];
  const float* qkv_b = (const float*)d_in[4];
  const float* proj_w = (const float*)d_in[5];
  const float* proj_b = (const float*)d_in[6];
  float* out = (float*)d_out;
  char* ws = (char*)d_ws;
  u16* wq = (u16*)(ws);                      // 1,572,864
  u16* wp = (u16*)(ws + 1572864);            //   524,288
  u16* ht = (u16*)(ws + 2097152);            // 16,777,216 (reused as aoT)
  u16* qkvo = (u16*)(ws + 18874368);         // 50,331,648 (only v band used)
  u16* qT = (u16*)(ws + 69206016);           // 16,777,216
  u16* kT = (u16*)(ws + 85983232);           // 16,777,216
  u16* aoT = ht;

  cast2_kernel<<<4096, 256, 0, stream>>>(qkv_w, proj_w, wq, wp, M3_ * K_, C_ * K_);
  gnorm_kernel<<<512, 256, 0, stream>>>(x, gamma, beta, ht);
  gemm_kernel<0><<<dim3(128, 12), 256, 0, stream>>>(wq, ht, qkv_b, qkvo, qT, kT, nullptr, nullptr);
  attn_kernel<<<1024, 256, 0, stream>>>(qT, kT, qkvo, aoT);
  gemm_kernel<1><<<dim3(128, 4), 256, 0, stream>>>(wp, aoT, proj_b, nullptr, nullptr, nullptr, x, out);
}

// Round 11
// 128.790 us; speedup vs baseline: 1.5665x; 1.0126x over previous
//
#include <hip/hip_runtime.h>

typedef unsigned short u16;
typedef unsigned int u32;
typedef __bf16 bf16x8 __attribute__((ext_vector_type(8)));
typedef float f32x4 __attribute__((ext_vector_type(4)));
typedef float f32x16 __attribute__((ext_vector_type(16)));

#define B_ 16
#define C_ 512
#define N_ 1024
#define NB_ 16384   // B_*N_
#define K_ 512
#define M3_ 1536
#define SCALE_Q 0.18033688011112042f  // 0.125 * log2(e)

// ---- helpers ----
__device__ __forceinline__ u16 f2bf(float f) {
  u32 u = __float_as_uint(f);
  u32 r = (u + 0x7FFFu + ((u >> 16) & 1u)) >> 16;  // RNE
  return (u16)r;
}

__device__ __forceinline__ void gl_lds16(const void* g, void* l) {
  __builtin_amdgcn_global_load_lds(
      (const __attribute__((address_space(1))) u32*)(uintptr_t)g,
      (__attribute__((address_space(3))) u32*)(u32)(uintptr_t)l, 16, 0, 0);
}

__device__ __forceinline__ u32 cvtpk(float lo, float hi) {
  u32 r;
  asm("v_cvt_pk_bf16_f32 %0, %1, %2" : "=v"(r) : "v"(lo), "v"(hi));
  return r;
}

__device__ __forceinline__ float exp2a(float x) {
  float r;
  asm("v_exp_f32 %0, %1" : "=v"(r) : "v"(x));
  return r;
}

// (a,b) -> a' = {a_lo, b_lo}, b' = {a_hi, b_hi}
__device__ __forceinline__ void plswap2(u32& a, u32& b) {
#if __has_builtin(__builtin_amdgcn_permlane32_swap)
  auto r = __builtin_amdgcn_permlane32_swap((int)a, (int)b, false, false);
  a = (u32)r[0];
  b = (u32)r[1];
#else
  asm("v_permlane32_swap_b32 %0, %1" : "+v"(a), "+v"(b));
#endif
}

__device__ __forceinline__ float xhalf_sum(float x) {
  u32 a = __float_as_uint(x), b = a;
  plswap2(a, b);
  return __uint_as_float(a) + __uint_as_float(b);
}

// ---- kernel 1: fp32 -> bf16 cast for both weight matrices (one launch) ----
__global__ __launch_bounds__(256) void cast2_kernel(const float* __restrict__ a,
                                                    const float* __restrict__ b,
                                                    u16* __restrict__ da,
                                                    u16* __restrict__ db,
                                                    int na, int nb) {
  int i = blockIdx.x * 256 + threadIdx.x;
  if (i < na) {
    da[i] = f2bf(a[i]);
  } else {
    int j = i - na;
    if (j < nb) db[j] = f2bf(b[j]);
  }
}

// ---- kernel 2: GroupNorm, writes h^T as (B*N, C) bf16 ----
__global__ __launch_bounds__(256) void gnorm_kernel(const float* __restrict__ x,
                                                    const float* __restrict__ gamma,
                                                    const float* __restrict__ beta,
                                                    u16* __restrict__ ht) {
  int blk = blockIdx.x;
  int b = blk >> 5, g = blk & 31;
  int t = threadIdx.x;
  const float* xb = x + ((size_t)(b * C_ + g * 16) << 10);
  float v[16][4];
  float s = 0.f, sq = 0.f;
#pragma unroll
  for (int cc = 0; cc < 16; ++cc) {
#pragma unroll
    for (int r = 0; r < 4; ++r) {
      float f = xb[cc * 1024 + r * 256 + t];
      v[cc][r] = f; s += f; sq += f * f;
    }
  }
#pragma unroll
  for (int m = 32; m >= 1; m >>= 1) { s += __shfl_xor(s, m, 64); sq += __shfl_xor(sq, m, 64); }
  __shared__ float red[8];
  int w = t >> 6;
  if ((t & 63) == 0) { red[w * 2] = s; red[w * 2 + 1] = sq; }
  __syncthreads();
  s = red[0] + red[2] + red[4] + red[6];
  sq = red[1] + red[3] + red[5] + red[7];
  float mean = s * (1.f / 16384.f);
  float var = sq * (1.f / 16384.f) - mean * mean;
  float rstd = rsqrtf(var + 1e-5f);
  float gm[16], bt[16];
#pragma unroll
  for (int cc = 0; cc < 16; ++cc) {
    gm[cc] = gamma[g * 16 + cc] * rstd;
    bt[cc] = beta[g * 16 + cc];
  }
  u16* hb = ht + ((size_t)(b << 10)) * C_ + g * 16;
#pragma unroll
  for (int r = 0; r < 4; ++r) {
    u32 pk[8];
#pragma unroll
    for (int q = 0; q < 8; ++q) {
      float f0 = (v[2 * q][r] - mean) * gm[2 * q] + bt[2 * q];
      float f1 = (v[2 * q + 1][r] - mean) * gm[2 * q + 1] + bt[2 * q + 1];
      pk[q] = (u32)f2bf(f0) | ((u32)f2bf(f1) << 16);
    }
    u16* dp = hb + (size_t)(r * 256 + t) * C_;
    uint4 a = {pk[0], pk[1], pk[2], pk[3]};
    uint4 b4 = {pk[4], pk[5], pk[6], pk[7]};
    *(uint4*)dp = a;
    *(uint4*)(dp + 8) = b4;
  }
}

// ---- GEMM (r6 body + XCD swizzle): C[MxNB] = A[MxK]*BT[NBxK]^T; 128x128, BK=64 ----
// EPI 0: qkv GEMM. q,k bands (rows<1024) stored TRANSPOSED per-(b,h) as (n,d)
//        bf16 into qTo/kTo (q pre-scaled); v band stored (o, bn) in Co.
// EPI 1: out = x + val + bias -> fp32 (b,c,n)
template <int EPI>
__global__ __launch_bounds__(256) void gemm_kernel(const u16* __restrict__ A,
                                                   const u16* __restrict__ BT,
                                                   const float* __restrict__ bias,
                                                   u16* __restrict__ Co,
                                                   u16* __restrict__ qTo,
                                                   u16* __restrict__ kTo,
                                                   const float* __restrict__ xres,
                                                   float* __restrict__ Fo) {
  __shared__ u16 ldsA[128 * 64];
  __shared__ u16 ldsB[128 * 64];
  int t = threadIdx.x;
  int l = t & 63, w = t >> 6;
  int wr = w >> 1, wc = w & 1;
  int lid = blockIdx.y * 128 + blockIdx.x;
  int xcd = lid & 7, j2 = lid >> 3;
  int bx = xcd * 16 + (j2 & 15);
  int by = j2 >> 4;
  int ro0 = by * 128, co0 = bx * 128;
  f32x4 acc[4][4];
#pragma unroll
  for (int m = 0; m < 4; ++m)
#pragma unroll
    for (int n = 0; n < 4; ++n) acc[m][n] = {0.f, 0.f, 0.f, 0.f};
  int srow = t >> 3, sg = t & 7;
  for (int kt = 0; kt < 8; ++kt) {
    int k0 = kt * 64;
#pragma unroll
    for (int i = 0; i < 4; ++i) {
      int row = i * 32 + srow;
      int gl = sg ^ (row & 7);
      gl_lds16(A + (size_t)(ro0 + row) * K_ + k0 + gl * 8, ldsA + (i * 32 + w * 8) * 64);
      gl_lds16(BT + (size_t)(co0 + row) * K_ + k0 + gl * 8, ldsB + (i * 32 + w * 8) * 64);
    }
    __syncthreads();
#pragma unroll
    for (int ks = 0; ks < 2; ++ks) {
      bf16x8 af[4], bfr[4];
#pragma unroll
      for (int m = 0; m < 4; ++m) {
        int row = wr * 64 + m * 16 + (l & 15);
        int ph = (ks * 4 + (l >> 4)) ^ (row & 7);
        af[m] = *(const bf16x8*)&ldsA[row * 64 + ph * 8];
      }
#pragma unroll
      for (int n = 0; n < 4; ++n) {
        int row = wc * 64 + n * 16 + (l & 15);
        int ph = (ks * 4 + (l >> 4)) ^ (row & 7);
        bfr[n] = *(const bf16x8*)&ldsB[row * 64 + ph * 8];
      }
#pragma unroll
      for (int m = 0; m < 4; ++m)
#pragma unroll
        for (int n = 0; n < 4; ++n)
          acc[m][n] = __builtin_amdgcn_mfma_f32_16x16x32_bf16(af[m], bfr[n], acc[m][n], 0, 0, 0);
    }
    __syncthreads();
  }
  if (EPI == 0 && ro0 < 1024) {
    int sel = ro0 >> 9;
    u16* dstb = sel ? kTo : qTo;
    float scl = sel ? 1.f : SCALE_Q;
#pragma unroll
    for (int m = 0; m < 4; ++m) {
      int row0 = ro0 + wr * 64 + m * 16 + (l >> 4) * 4;
      int o = row0 & 511;
      int h = o >> 6, d0 = o & 63;
      float bv0 = bias[row0], bv1 = bias[row0 + 1];
      float bv2 = bias[row0 + 2], bv3 = bias[row0 + 3];
#pragma unroll
      for (int n = 0; n < 4; ++n) {
        int col = co0 + wc * 64 + n * 16 + (l & 15);
        int bb = col >> 10, nn = col & 1023;
        float v0 = (acc[m][n][0] + bv0) * scl;
        float v1 = (acc[m][n][1] + bv1) * scl;
        float v2 = (acc[m][n][2] + bv2) * scl;
        float v3 = (acc[m][n][3] + bv3) * scl;
        uint2 ov = {cvtpk(v0, v1), cvtpk(v2, v3)};
        *(uint2*)(dstb + ((size_t)((bb * 8 + h) << 10) + nn) * 64 + d0) = ov;
      }
    }
  } else {
#pragma unroll
    for (int m = 0; m < 4; ++m) {
#pragma unroll
      for (int j = 0; j < 4; ++j) {
        int row = ro0 + wr * 64 + m * 16 + (l >> 4) * 4 + j;
        float bv = bias[row];
#pragma unroll
        for (int n = 0; n < 4; ++n) {
          int col = co0 + wc * 64 + n * 16 + (l & 15);
          float val = acc[m][n][j] + bv;
          if (EPI == 0) {
            Co[(size_t)row * NB_ + col] = f2bf(val);
          } else {
            int bb = col >> 10, nn = col & 1023;
            size_t oi = (((size_t)(bb * C_ + row)) << 10) + nn;
            Fo[oi] = xres[oi] + val;
          }
        }
      }
    }
  }
}

// ---- kernel 4: flash attention, 4 waves x 32 q-rows, KVBLK=32, T15 pipeline ----
// Iteration s overlaps QK(s+1) (MFMA, from tile staged last iter) with the
// softmax-finish + PV of tile s (VALU+MFMA on last iter's QK output). 3 LDS
// buffers (rotating pointers); tile s's buffer is overwritten only at iter s+1
// AFTER the barrier that retires all its readers (r6 discipline). scA/scB are
// statically named via 2-step manual unroll (rule #20).
__global__ __launch_bounds__(256) void attn_kernel(const u16* __restrict__ qT,
                                                   const u16* __restrict__ kT,
                                                   const u16* __restrict__ qkv,
                                                   u16* __restrict__ aoT) {
  __shared__ u16 KV[3][4096];  // [buf][0..2047 = K(32kv x 64d) | 2048..4095 = V(64d x 32kv)]
  int bid = blockIdx.x;
  int wid = (bid & 7) * 128 + (bid >> 3);  // XCD swizzle: 8 blocks of a head on one XCD
  int qt2 = wid & 7, h = (wid >> 3) & 7, b = wid >> 6;
  int bh = b * 8 + h;
  int t = threadIdx.x, l = t & 63, w = t >> 6;
  int lq = l & 31, hi = l >> 5;
  int q0 = qt2 * 128 + w * 32;

  // Q fragments (scale pre-folded in qkv GEMM epilogue)
  const u16* qbase = qT + ((size_t)(bh << 10) + q0 + lq) * 64 + hi * 8;
  bf16x8 qf[4];
#pragma unroll
  for (int kc = 0; kc < 4; ++kc) qf[kc] = *(const bf16x8*)(qbase + kc * 16);

  f32x16 accO[2];
#pragma unroll
  for (int dt = 0; dt < 2; ++dt)
#pragma unroll
    for (int r = 0; r < 16; ++r) accO[dt][r] = 0.f;
  float lsum = 0.f;

  // staging: 8 gl_lds16 per tile, wave w issues 2 (r6-verbatim layout)
  const u16 *src0, *src1;
  u32 ldso0, ldso1;
  int adv;
  if (w < 2) {
    int i0 = 2 * w, i1 = 2 * w + 1;
    src0 = kT + ((size_t)(bh << 10) + i0 * 8 + (l >> 3)) * 64 + (((l & 7) ^ ((l >> 3) & 7)) * 8);
    src1 = kT + ((size_t)(bh << 10) + i1 * 8 + (l >> 3)) * 64 + (((l & 7) ^ ((l >> 3) & 7)) * 8);
    ldso0 = i0 * 512; ldso1 = i1 * 512;
    adv = 2048;  // 32 kv-rows * 64
  } else {
    int j0 = 2 * (w - 2), j1 = 2 * (w - 2) + 1;
    src0 = qkv + (size_t)(2 * C_ + h * 64 + j0 * 16 + (l >> 2)) * NB_ + (b << 10) +
           (((l & 3) ^ ((l >> 3) & 3)) * 8);
    src1 = qkv + (size_t)(2 * C_ + h * 64 + j1 * 16 + (l >> 2)) * NB_ + (b << 10) +
           (((l & 3) ^ ((l >> 3) & 3)) * 8);
    ldso0 = 2048 + j0 * 512; ldso1 = 2048 + j1 * 512;
    adv = 32;    // 32 kv-cols
  }

  // LDS read offsets (relative to a buffer base; r6-verbatim)
  u32 kfo[4], vfo[4];
#pragma unroll
  for (int kc = 0; kc < 4; ++kc)
    kfo[kc] = lq * 64 + (((2 * kc + hi) ^ (lq & 7)) * 8);
#pragma unroll
  for (int dt = 0; dt < 2; ++dt)
#pragma unroll
    for (int kcc = 0; kcc < 2; ++kcc)
      vfo[dt * 2 + kcc] = 2048 + (dt * 32 + lq) * 32 + (((kcc * 2 + hi) ^ ((lq >> 1) & 3)) * 8);

  auto stageTo = [&](u16* buf) {
    gl_lds16(src0, buf + ldso0);
    gl_lds16(src1, buf + ldso1);
    src0 += adv;
    src1 += adv;
  };

  auto qk = [&](const u16* buf, f32x16& sc) {
    bf16x8 kf[4];
#pragma unroll
    for (int kc = 0; kc < 4; ++kc) kf[kc] = *(const bf16x8*)(buf + kfo[kc]);
#pragma unroll
    for (int r = 0; r < 16; ++r) sc[r] = 0.f;
    __builtin_amdgcn_s_setprio(1);
#pragma unroll
    for (int kc = 0; kc < 4; ++kc)
      sc = __builtin_amdgcn_mfma_f32_32x32x16_bf16(kf[kc], qf[kc], sc, 0, 0, 0);
    __builtin_amdgcn_s_setprio(0);
  };

  auto finish = [&](const u16* buf, f32x16& sc) {
    bf16x8 vf[4];
#pragma unroll
    for (int j = 0; j < 4; ++j) vf[j] = *(const bf16x8*)(buf + vfo[j]);
    // P = exp2(S); log2-domain scores, constant shift cancels in O = PV / sum P
    float p0 = 0.f, p1 = 0.f, p2 = 0.f, p3 = 0.f;
#pragma unroll
    for (int r = 0; r < 4; ++r) {
      float e0 = exp2a(sc[4 * r + 0]);
      float e1 = exp2a(sc[4 * r + 1]);
      float e2 = exp2a(sc[4 * r + 2]);
      float e3 = exp2a(sc[4 * r + 3]);
      sc[4 * r + 0] = e0; sc[4 * r + 1] = e1;
      sc[4 * r + 2] = e2; sc[4 * r + 3] = e3;
      p0 += e0; p1 += e1; p2 += e2; p3 += e3;
    }
    lsum += (p0 + p1) + (p2 + p3);
    u32 pk[8];
#pragma unroll
    for (int p = 0; p < 8; ++p) pk[p] = cvtpk(sc[2 * p], sc[2 * p + 1]);
    u32 pfu[2][4];
#pragma unroll
    for (int cc = 0; cc < 2; ++cc) {
      u32 w0 = pk[cc * 4 + 0], w2 = pk[cc * 4 + 2];
      u32 w1 = pk[cc * 4 + 1], w3 = pk[cc * 4 + 3];
      plswap2(w0, w2);
      plswap2(w1, w3);
      pfu[cc][0] = w0; pfu[cc][1] = w1; pfu[cc][2] = w2; pfu[cc][3] = w3;
    }
    __builtin_amdgcn_s_setprio(1);
#pragma unroll
    for (int kcc = 0; kcc < 2; ++kcc)
#pragma unroll
      for (int dt = 0; dt < 2; ++dt) {
        union { u32 u[4]; bf16x8 v; } pf;
        pf.u[0] = pfu[kcc][0]; pf.u[1] = pfu[kcc][1];
        pf.u[2] = pfu[kcc][2]; pf.u[3] = pfu[kcc][3];
        accO[dt] = __builtin_amdgcn_mfma_f32_32x32x16_bf16(vf[dt * 2 + kcc], pf.v, accO[dt], 0, 0, 0);
      }
    __builtin_amdgcn_s_setprio(0);
  };

#define WAITBAR(N)                                       \
  asm volatile("s_waitcnt vmcnt(" #N ")" ::: "memory"); \
  __builtin_amdgcn_sched_barrier(0);                     \
  __builtin_amdgcn_s_barrier();                          \
  __builtin_amdgcn_sched_barrier(0);

  u16* pa = &KV[0][0];
  u16* pb = &KV[1][0];
  u16* pc = &KV[2][0];
  f32x16 scA, scB;

  stageTo(pa);  // tile 0
  stageTo(pb);  // tile 1
  WAITBAR(0)    // tile 0 (and 1) fully in LDS for all waves
  qk(pa, scA);  // QK(0)

#pragma unroll 1
  for (int s = 0; s < 15; ++s) {
    // iter 2s: QK(2s+1) || finish(2s)
    WAITBAR(0)
    stageTo(pc);        // tile 2s+2 (pc's old readers retired at barrier above)
    qk(pb, scB);
    finish(pa, scA);
    u16* tp = pa; pa = pb; pb = pc; pc = tp;
    // iter 2s+1: QK(2s+2) || finish(2s+1)
    WAITBAR(0)
    stageTo(pc);        // tile 2s+3
    qk(pb, scA);
    finish(pa, scB);
    tp = pa; pa = pb; pb = pc; pc = tp;
  }
  // iter 30: QK(31) || finish(30); tile 31 landed (staged at iter 29)
  WAITBAR(0)
  qk(pb, scB);
  finish(pa, scA);
  pa = pb;
  // iter 31: finish(31) (tile-31 visibility guaranteed by iter-30 barrier)
  finish(pa, scB);
#undef WAITBAR

  float inv = 1.0f / xhalf_sum(lsum);
  u16* ob = aoT + ((size_t)((b << 10) + q0 + lq)) * C_ + h * 64;
#pragma unroll
  for (int dt = 0; dt < 2; ++dt)
#pragma unroll
    for (int rg = 0; rg < 4; ++rg) {
      int d0 = dt * 32 + rg * 8 + hi * 4;
      u32 w0 = cvtpk(accO[dt][rg * 4 + 0] * inv, accO[dt][rg * 4 + 1] * inv);
      u32 w1 = cvtpk(accO[dt][rg * 4 + 2] * inv, accO[dt][rg * 4 + 3] * inv);
      uint2 o = {w0, w1};
      *(uint2*)(ob + d0) = o;
    }
}

// ---- launcher ----
extern "C" void kernel_launch(void* const* d_in, const int* in_sizes, int n_in,
                              void* d_out, int out_size, void* d_ws, size_t ws_size,
                              hipStream_t stream) {
  const float* x = (const float*)d_in[0];
  const float* gamma = (const float*)d_in[1];
  const float* beta = (const float*)d_in[2];
  const float* qkv_w = (const float*)d_in[3];
  const float* qkv_b = (const float*)d_in[4];
  const float* proj_w = (const float*)d_in[5];
  const float* proj_b = (const float*)d_in[6];
  float* out = (float*)d_out;
  char* ws = (char*)d_ws;
  u16* wq = (u16*)(ws);                      // 1,572,864
  u16* wp = (u16*)(ws + 1572864);            //   524,288
  u16* ht = (u16*)(ws + 2097152);            // 16,777,216 (reused as aoT)
  u16* qkvo = (u16*)(ws + 18874368);         // 50,331,648 (only v band used)
  u16* qT = (u16*)(ws + 69206016);           // 16,777,216
  u16* kT = (u16*)(ws + 85983232);           // 16,777,216
  u16* aoT = ht;

  cast2_kernel<<<4096, 256, 0, stream>>>(qkv_w, proj_w, wq, wp, M3_ * K_, C_ * K_);
  gnorm_kernel<<<512, 256, 0, stream>>>(x, gamma, beta, ht);
  gemm_kernel<0><<<dim3(128, 12), 256, 0, stream>>>(wq, ht, qkv_b, qkvo, qT, kT, nullptr, nullptr);
  attn_kernel<<<1024, 256, 0, stream>>>(qT, kT, qkvo, aoT);
  gemm_kernel<1><<<dim3(128, 4), 256, 0, stream>>>(wp, aoT, proj_b, nullptr, nullptr, nullptr, x, out);
}

// Round 12
// 123.855 us; speedup vs baseline: 1.6289x; 1.0398x over previous
//
#include <hip/hip_runtime.h>

typedef unsigned short u16;
typedef unsigned int u32;
typedef __bf16 bf16x8 __attribute__((ext_vector_type(8)));
typedef float f32x4 __attribute__((ext_vector_type(4)));
typedef float f32x16 __attribute__((ext_vector_type(16)));

#define B_ 16
#define C_ 512
#define N_ 1024
#define NB_ 16384   // B_*N_
#define K_ 512
#define M3_ 1536
#define SCALE_Q 0.18033688011112042f  // 0.125 * log2(e)

// ---- helpers ----
__device__ __forceinline__ u16 f2bf(float f) {
  u32 u = __float_as_uint(f);
  u32 r = (u + 0x7FFFu + ((u >> 16) & 1u)) >> 16;  // RNE
  return (u16)r;
}

__device__ __forceinline__ void gl_lds16(const void* g, void* l) {
  __builtin_amdgcn_global_load_lds(
      (const __attribute__((address_space(1))) u32*)(uintptr_t)g,
      (__attribute__((address_space(3))) u32*)(u32)(uintptr_t)l, 16, 0, 0);
}

__device__ __forceinline__ u32 cvtpk(float lo, float hi) {
  u32 r;
  asm("v_cvt_pk_bf16_f32 %0, %1, %2" : "=v"(r) : "v"(lo), "v"(hi));
  return r;
}

__device__ __forceinline__ float exp2a(float x) {
  float r;
  asm("v_exp_f32 %0, %1" : "=v"(r) : "v"(x));
  return r;
}

// (a,b) -> a' = {a_lo, b_lo}, b' = {a_hi, b_hi}
__device__ __forceinline__ void plswap2(u32& a, u32& b) {
#if __has_builtin(__builtin_amdgcn_permlane32_swap)
  auto r = __builtin_amdgcn_permlane32_swap((int)a, (int)b, false, false);
  a = (u32)r[0];
  b = (u32)r[1];
#else
  asm("v_permlane32_swap_b32 %0, %1" : "+v"(a), "+v"(b));
#endif
}

__device__ __forceinline__ float xhalf_sum(float x) {
  u32 a = __float_as_uint(x), b = a;
  plswap2(a, b);
  return __uint_as_float(a) + __uint_as_float(b);
}

// ---- kernel 1: fp32 -> bf16 cast for both weight matrices (one launch) ----
__global__ __launch_bounds__(256) void cast2_kernel(const float* __restrict__ a,
                                                    const float* __restrict__ b,
                                                    u16* __restrict__ da,
                                                    u16* __restrict__ db,
                                                    int na, int nb) {
  int i = blockIdx.x * 256 + threadIdx.x;
  if (i < na) {
    da[i] = f2bf(a[i]);
  } else {
    int j = i - na;
    if (j < nb) db[j] = f2bf(b[j]);
  }
}

// ---- kernel 2: GroupNorm, writes h^T as (B*N, C) bf16 ----
__global__ __launch_bounds__(256) void gnorm_kernel(const float* __restrict__ x,
                                                    const float* __restrict__ gamma,
                                                    const float* __restrict__ beta,
                                                    u16* __restrict__ ht) {
  int blk = blockIdx.x;
  int b = blk >> 5, g = blk & 31;
  int t = threadIdx.x;
  const float* xb = x + ((size_t)(b * C_ + g * 16) << 10);
  float v[16][4];
  float s = 0.f, sq = 0.f;
#pragma unroll
  for (int cc = 0; cc < 16; ++cc) {
#pragma unroll
    for (int r = 0; r < 4; ++r) {
      float f = xb[cc * 1024 + r * 256 + t];
      v[cc][r] = f; s += f; sq += f * f;
    }
  }
#pragma unroll
  for (int m = 32; m >= 1; m >>= 1) { s += __shfl_xor(s, m, 64); sq += __shfl_xor(sq, m, 64); }
  __shared__ float red[8];
  int w = t >> 6;
  if ((t & 63) == 0) { red[w * 2] = s; red[w * 2 + 1] = sq; }
  __syncthreads();
  s = red[0] + red[2] + red[4] + red[6];
  sq = red[1] + red[3] + red[5] + red[7];
  float mean = s * (1.f / 16384.f);
  float var = sq * (1.f / 16384.f) - mean * mean;
  float rstd = rsqrtf(var + 1e-5f);
  float gm[16], bt[16];
#pragma unroll
  for (int cc = 0; cc < 16; ++cc) {
    gm[cc] = gamma[g * 16 + cc] * rstd;
    bt[cc] = beta[g * 16 + cc];
  }
  u16* hb = ht + ((size_t)(b << 10)) * C_ + g * 16;
#pragma unroll
  for (int r = 0; r < 4; ++r) {
    u32 pk[8];
#pragma unroll
    for (int q = 0; q < 8; ++q) {
      float f0 = (v[2 * q][r] - mean) * gm[2 * q] + bt[2 * q];
      float f1 = (v[2 * q + 1][r] - mean) * gm[2 * q + 1] + bt[2 * q + 1];
      pk[q] = (u32)f2bf(f0) | ((u32)f2bf(f1) << 16);
    }
    u16* dp = hb + (size_t)(r * 256 + t) * C_;
    uint4 a = {pk[0], pk[1], pk[2], pk[3]};
    uint4 b4 = {pk[4], pk[5], pk[6], pk[7]};
    *(uint4*)dp = a;
    *(uint4*)(dp + 8) = b4;
  }
}

// ---- GEMM, 16-phase counted-vmcnt pipeline (T3+T4+T5) ----
// C[MxNB] = A[MxK]*BT[NBxK]^T; 128x128 tile, half-tiles of BK=32, 4 waves.
// LDS = 4 rotating half-buffers (16KB each: A[128x32] | B[128x32]); prologue
// stages 3 halves; each phase: vmcnt(8) (own 4 loads of half h done, 8 newer
// in flight - never drained) -> s_barrier -> stage half h+3 (overwrites buf
// h-1, readers retired at this barrier) -> 8 ds_read_b128 -> 16 MFMA (setprio).
// Swizzle: 64B rows, key=(row>>1)&3; store granule (l&3)^((l>>3)&3), read slot
// (l>>4)^((l>>1)&3) -> 2-way bank aliasing (free).
// EPI 0: qkv GEMM. q,k bands (rows<1024) stored TRANSPOSED per-(b,h) as (n,d)
//        bf16 into qTo/kTo (q pre-scaled); v band stored (o, bn) in Co.
// EPI 1: out = x + val + bias -> fp32 (b,c,n)
template <int EPI>
__global__ __launch_bounds__(256) void gemm_kernel(const u16* __restrict__ A,
                                                   const u16* __restrict__ BT,
                                                   const float* __restrict__ bias,
                                                   u16* __restrict__ Co,
                                                   u16* __restrict__ qTo,
                                                   u16* __restrict__ kTo,
                                                   const float* __restrict__ xres,
                                                   float* __restrict__ Fo) {
  __shared__ __attribute__((aligned(16))) u16 lds[4][8192];  // [half-buf][A:0..4095 | B:4096..8191]
  int t = threadIdx.x;
  int l = t & 63, w = t >> 6;
  int wr = w >> 1, wc = w & 1;
  int lid = blockIdx.y * 128 + blockIdx.x;
  int xcd = lid & 7, j2 = lid >> 3;
  int bx = xcd * 16 + (j2 & 15);
  int by = j2 >> 4;
  int ro0 = by * 128, co0 = bx * 128;
  f32x4 acc[4][4];
#pragma unroll
  for (int m = 0; m < 4; ++m)
#pragma unroll
    for (int n = 0; n < 4; ++n) acc[m][n] = {0.f, 0.f, 0.f, 0.f};

  // staging: per half, 8 A-instrs + 8 B-instrs (1KB each); wave w issues A{2w,2w+1}, B{2w,2w+1}.
  // instr i covers rows [i*16, i*16+16): lane l -> row i*16+(l>>2), slot l&3,
  // source granule = (l&3)^((l>>3)&3)  (key(row) = (row>>1)&3 = (l>>3)&3 here).
  int gsrc = ((l & 3) ^ ((l >> 3) & 3)) * 8;
  const u16* sA0 = A + (size_t)(ro0 + 2 * w * 16 + (l >> 2)) * K_ + gsrc;
  const u16* sA1 = sA0 + (size_t)16 * K_;
  const u16* sB0 = BT + (size_t)(co0 + 2 * w * 16 + (l >> 2)) * K_ + gsrc;
  const u16* sB1 = sB0 + (size_t)16 * K_;
  u32 dA0 = (2 * w) * 512, dA1 = (2 * w + 1) * 512;
  u32 dB0 = 4096 + (2 * w) * 512, dB1 = 4096 + (2 * w + 1) * 512;

  auto stage = [&](int hb) {
    u16* base = &lds[hb][0];
    gl_lds16(sA0, base + dA0);
    gl_lds16(sA1, base + dA1);
    gl_lds16(sB0, base + dB0);
    gl_lds16(sB1, base + dB1);
    sA0 += 32; sA1 += 32; sB0 += 32; sB1 += 32;
  };

  // read: row = (wr|wc)*64 + m*16 + (l&15); slot = (l>>4)^((l>>1)&3); addr = row*32 + slot*8
  u32 slot = (((l >> 4) ^ (l >> 1)) & 3) * 8;
  u32 aro = (wr * 64 + (l & 15)) * 32 + slot;
  u32 bro = 4096 + (wc * 64 + (l & 15)) * 32 + slot;

  auto compute = [&](int hb) {
    const u16* base = &lds[hb][0];
    bf16x8 af[4], bfr[4];
#pragma unroll
    for (int m = 0; m < 4; ++m) af[m] = *(const bf16x8*)(base + aro + m * 512);
#pragma unroll
    for (int n = 0; n < 4; ++n) bfr[n] = *(const bf16x8*)(base + bro + n * 512);
    __builtin_amdgcn_s_setprio(1);
#pragma unroll
    for (int m = 0; m < 4; ++m)
#pragma unroll
      for (int n = 0; n < 4; ++n)
        acc[m][n] = __builtin_amdgcn_mfma_f32_16x16x32_bf16(af[m], bfr[n], acc[m][n], 0, 0, 0);
    __builtin_amdgcn_s_setprio(0);
  };

#define PHASE_SYNC(N)                                    \
  asm volatile("s_waitcnt vmcnt(" #N ")" ::: "memory"); \
  __builtin_amdgcn_sched_barrier(0);                     \
  __builtin_amdgcn_s_barrier();                          \
  __builtin_amdgcn_sched_barrier(0);

  stage(0);
  stage(1);
  stage(2);
#pragma unroll 1
  for (int h = 0; h < 13; ++h) {
    PHASE_SYNC(8)
    stage((h + 3) & 3);
    compute(h & 3);
  }
  PHASE_SYNC(8)
  compute(1);  // h=13
  PHASE_SYNC(4)
  compute(2);  // h=14
  PHASE_SYNC(0)
  compute(3);  // h=15
#undef PHASE_SYNC

  if (EPI == 0 && ro0 < 1024) {
    int sel = ro0 >> 9;
    u16* dstb = sel ? kTo : qTo;
    float scl = sel ? 1.f : SCALE_Q;
#pragma unroll
    for (int m = 0; m < 4; ++m) {
      int row0 = ro0 + wr * 64 + m * 16 + (l >> 4) * 4;
      int o = row0 & 511;
      int h2 = o >> 6, d0 = o & 63;
      float bv0 = bias[row0], bv1 = bias[row0 + 1];
      float bv2 = bias[row0 + 2], bv3 = bias[row0 + 3];
#pragma unroll
      for (int n = 0; n < 4; ++n) {
        int col = co0 + wc * 64 + n * 16 + (l & 15);
        int bb = col >> 10, nn = col & 1023;
        float v0 = (acc[m][n][0] + bv0) * scl;
        float v1 = (acc[m][n][1] + bv1) * scl;
        float v2 = (acc[m][n][2] + bv2) * scl;
        float v3 = (acc[m][n][3] + bv3) * scl;
        uint2 ov = {cvtpk(v0, v1), cvtpk(v2, v3)};
        *(uint2*)(dstb + ((size_t)((bb * 8 + h2) << 10) + nn) * 64 + d0) = ov;
      }
    }
  } else {
#pragma unroll
    for (int m = 0; m < 4; ++m) {
#pragma unroll
      for (int j = 0; j < 4; ++j) {
        int row = ro0 + wr * 64 + m * 16 + (l >> 4) * 4 + j;
        float bv = bias[row];
#pragma unroll
        for (int n = 0; n < 4; ++n) {
          int col = co0 + wc * 64 + n * 16 + (l & 15);
          float val = acc[m][n][j] + bv;
          if (EPI == 0) {
            Co[(size_t)row * NB_ + col] = f2bf(val);
          } else {
            int bb = col >> 10, nn = col & 1023;
            size_t oi = (((size_t)(bb * C_ + row)) << 10) + nn;
            Fo[oi] = xres[oi] + val;
          }
        }
      }
    }
  }
}

// ---- kernel 4: flash attention, 4 waves x 32 q-rows, KVBLK=32, T15 pipeline ----
// (r11-exact: passed, ~47us)
__global__ __launch_bounds__(256) void attn_kernel(const u16* __restrict__ qT,
                                                   const u16* __restrict__ kT,
                                                   const u16* __restrict__ qkv,
                                                   u16* __restrict__ aoT) {
  __shared__ u16 KV[3][4096];  // [buf][0..2047 = K(32kv x 64d) | 2048..4095 = V(64d x 32kv)]
  int bid = blockIdx.x;
  int wid = (bid & 7) * 128 + (bid >> 3);  // XCD swizzle: 8 blocks of a head on one XCD
  int qt2 = wid & 7, h = (wid >> 3) & 7, b = wid >> 6;
  int bh = b * 8 + h;
  int t = threadIdx.x, l = t & 63, w = t >> 6;
  int lq = l & 31, hi = l >> 5;
  int q0 = qt2 * 128 + w * 32;

  const u16* qbase = qT + ((size_t)(bh << 10) + q0 + lq) * 64 + hi * 8;
  bf16x8 qf[4];
#pragma unroll
  for (int kc = 0; kc < 4; ++kc) qf[kc] = *(const bf16x8*)(qbase + kc * 16);

  f32x16 accO[2];
#pragma unroll
  for (int dt = 0; dt < 2; ++dt)
#pragma unroll
    for (int r = 0; r < 16; ++r) accO[dt][r] = 0.f;
  float lsum = 0.f;

  const u16 *src0, *src1;
  u32 ldso0, ldso1;
  int adv;
  if (w < 2) {
    int i0 = 2 * w, i1 = 2 * w + 1;
    src0 = kT + ((size_t)(bh << 10) + i0 * 8 + (l >> 3)) * 64 + (((l & 7) ^ ((l >> 3) & 7)) * 8);
    src1 = kT + ((size_t)(bh << 10) + i1 * 8 + (l >> 3)) * 64 + (((l & 7) ^ ((l >> 3) & 7)) * 8);
    ldso0 = i0 * 512; ldso1 = i1 * 512;
    adv = 2048;  // 32 kv-rows * 64
  } else {
    int j0 = 2 * (w - 2), j1 = 2 * (w - 2) + 1;
    src0 = qkv + (size_t)(2 * C_ + h * 64 + j0 * 16 + (l >> 2)) * NB_ + (b << 10) +
           (((l & 3) ^ ((l >> 3) & 3)) * 8);
    src1 = qkv + (size_t)(2 * C_ + h * 64 + j1 * 16 + (l >> 2)) * NB_ + (b << 10) +
           (((l & 3) ^ ((l >> 3) & 3)) * 8);
    ldso0 = 2048 + j0 * 512; ldso1 = 2048 + j1 * 512;
    adv = 32;    // 32 kv-cols
  }

  u32 kfo[4], vfo[4];
#pragma unroll
  for (int kc = 0; kc < 4; ++kc)
    kfo[kc] = lq * 64 + (((2 * kc + hi) ^ (lq & 7)) * 8);
#pragma unroll
  for (int dt = 0; dt < 2; ++dt)
#pragma unroll
    for (int kcc = 0; kcc < 2; ++kcc)
      vfo[dt * 2 + kcc] = 2048 + (dt * 32 + lq) * 32 + (((kcc * 2 + hi) ^ ((lq >> 1) & 3)) * 8);

  auto stageTo = [&](u16* buf) {
    gl_lds16(src0, buf + ldso0);
    gl_lds16(src1, buf + ldso1);
    src0 += adv;
    src1 += adv;
  };

  auto qk = [&](const u16* buf, f32x16& sc) {
    bf16x8 kf[4];
#pragma unroll
    for (int kc = 0; kc < 4; ++kc) kf[kc] = *(const bf16x8*)(buf + kfo[kc]);
#pragma unroll
    for (int r = 0; r < 16; ++r) sc[r] = 0.f;
    __builtin_amdgcn_s_setprio(1);
#pragma unroll
    for (int kc = 0; kc < 4; ++kc)
      sc = __builtin_amdgcn_mfma_f32_32x32x16_bf16(kf[kc], qf[kc], sc, 0, 0, 0);
    __builtin_amdgcn_s_setprio(0);
  };

  auto finish = [&](const u16* buf, f32x16& sc) {
    bf16x8 vf[4];
#pragma unroll
    for (int j = 0; j < 4; ++j) vf[j] = *(const bf16x8*)(buf + vfo[j]);
    float p0 = 0.f, p1 = 0.f, p2 = 0.f, p3 = 0.f;
#pragma unroll
    for (int r = 0; r < 4; ++r) {
      float e0 = exp2a(sc[4 * r + 0]);
      float e1 = exp2a(sc[4 * r + 1]);
      float e2 = exp2a(sc[4 * r + 2]);
      float e3 = exp2a(sc[4 * r + 3]);
      sc[4 * r + 0] = e0; sc[4 * r + 1] = e1;
      sc[4 * r + 2] = e2; sc[4 * r + 3] = e3;
      p0 += e0; p1 += e1; p2 += e2; p3 += e3;
    }
    lsum += (p0 + p1) + (p2 + p3);
    u32 pk[8];
#pragma unroll
    for (int p = 0; p < 8; ++p) pk[p] = cvtpk(sc[2 * p], sc[2 * p + 1]);
    u32 pfu[2][4];
#pragma unroll
    for (int cc = 0; cc < 2; ++cc) {
      u32 w0 = pk[cc * 4 + 0], w2 = pk[cc * 4 + 2];
      u32 w1 = pk[cc * 4 + 1], w3 = pk[cc * 4 + 3];
      plswap2(w0, w2);
      plswap2(w1, w3);
      pfu[cc][0] = w0; pfu[cc][1] = w1; pfu[cc][2] = w2; pfu[cc][3] = w3;
    }
    __builtin_amdgcn_s_setprio(1);
#pragma unroll
    for (int kcc = 0; kcc < 2; ++kcc)
#pragma unroll
      for (int dt = 0; dt < 2; ++dt) {
        union { u32 u[4]; bf16x8 v; } pf;
        pf.u[0] = pfu[kcc][0]; pf.u[1] = pfu[kcc][1];
        pf.u[2] = pfu[kcc][2]; pf.u[3] = pfu[kcc][3];
        accO[dt] = __builtin_amdgcn_mfma_f32_32x32x16_bf16(vf[dt * 2 + kcc], pf.v, accO[dt], 0, 0, 0);
      }
    __builtin_amdgcn_s_setprio(0);
  };

#define WAITBAR(N)                                       \
  asm volatile("s_waitcnt vmcnt(" #N ")" ::: "memory"); \
  __builtin_amdgcn_sched_barrier(0);                     \
  __builtin_amdgcn_s_barrier();                          \
  __builtin_amdgcn_sched_barrier(0);

  u16* pa = &KV[0][0];
  u16* pb = &KV[1][0];
  u16* pc = &KV[2][0];
  f32x16 scA, scB;

  stageTo(pa);  // tile 0
  stageTo(pb);  // tile 1
  WAITBAR(0)
  qk(pa, scA);  // QK(0)

#pragma unroll 1
  for (int s = 0; s < 15; ++s) {
    WAITBAR(0)
    stageTo(pc);
    qk(pb, scB);
    finish(pa, scA);
    u16* tp = pa; pa = pb; pb = pc; pc = tp;
    WAITBAR(0)
    stageTo(pc);
    qk(pb, scA);
    finish(pa, scB);
    tp = pa; pa = pb; pb = pc; pc = tp;
  }
  WAITBAR(0)
  qk(pb, scB);
  finish(pa, scA);
  pa = pb;
  finish(pa, scB);
#undef WAITBAR

  float inv = 1.0f / xhalf_sum(lsum);
  u16* ob = aoT + ((size_t)((b << 10) + q0 + lq)) * C_ + h * 64;
#pragma unroll
  for (int dt = 0; dt < 2; ++dt)
#pragma unroll
    for (int rg = 0; rg < 4; ++rg) {
      int d0 = dt * 32 + rg * 8 + hi * 4;
      u32 w0 = cvtpk(accO[dt][rg * 4 + 0] * inv, accO[dt][rg * 4 + 1] * inv);
      u32 w1 = cvtpk(accO[dt][rg * 4 + 2] * inv, accO[dt][rg * 4 + 3] * inv);
      uint2 o = {w0, w1};
      *(uint2*)(ob + d0) = o;
    }
}

// ---- launcher ----
extern "C" void kernel_launch(void* const* d_in, const int* in_sizes, int n_in,
                              void* d_out, int out_size, void* d_ws, size_t ws_size,
                              hipStream_t stream) {
  const float* x = (const float*)d_in[0];
  const float* gamma = (const float*)d_in[1];
  const float* beta = (const float*)d_in[2];
  const float* qkv_w = (const float*)d_in[3];
  const float* qkv_b = (const float*)d_in[4];
  const float* proj_w = (const float*)d_in[5];
  const float* proj_b = (const float*)d_in[6];
  float* out = (float*)d_out;
  char* ws = (char*)d_ws;
  u16* wq = (u16*)(ws);                      // 1,572,864
  u16* wp = (u16*)(ws + 1572864);            //   524,288
  u16* ht = (u16*)(ws + 2097152);            // 16,777,216 (reused as aoT)
  u16* qkvo = (u16*)(ws + 18874368);         // 50,331,648 (only v band used)
  u16* qT = (u16*)(ws + 69206016);           // 16,777,216
  u16* kT = (u16*)(ws + 85983232);           // 16,777,216
  u16* aoT = ht;

  cast2_kernel<<<4096, 256, 0, stream>>>(qkv_w, proj_w, wq, wp, M3_ * K_, C_ * K_);
  gnorm_kernel<<<512, 256, 0, stream>>>(x, gamma, beta, ht);
  gemm_kernel<0><<<dim3(128, 12), 256, 0, stream>>>(wq, ht, qkv_b, qkvo, qT, kT, nullptr, nullptr);
  attn_kernel<<<1024, 256, 0, stream>>>(qT, kT, qkvo, aoT);
  gemm_kernel<1><<<dim3(128, 4), 256, 0, stream>>>(wp, aoT, proj_b, nullptr, nullptr, nullptr, x, out);
}